// Round 1
// baseline (258.030 us; speedup 1.0000x reference)
//
#include <hip/hip_runtime.h>
#include <stdint.h>

#define DIM   1024
#define NHEAD 16
#define HD    64
#define SEQ   2048
#define NTOK  4096
#define QKV_REGION (NTOK * DIM)   // 4194304 elements per Q/K/V region

typedef short          bf16x8 __attribute__((ext_vector_type(8)));
typedef float          f32x4  __attribute__((ext_vector_type(4)));
typedef unsigned short u16x8  __attribute__((ext_vector_type(8)));
typedef unsigned short u16x4  __attribute__((ext_vector_type(4)));

__device__ __forceinline__ unsigned short f2bf(float f) {
  union { float f; unsigned u; } x; x.f = f;
  unsigned r = x.u + 0x7FFFu + ((x.u >> 16) & 1u);  // RNE
  return (unsigned short)(r >> 16);
}

__device__ __forceinline__ void gld16(void* lds, const void* g) {
  __builtin_amdgcn_global_load_lds(
      (const __attribute__((address_space(1))) unsigned int*)g,
      (__attribute__((address_space(3))) unsigned int*)lds, 16, 0, 0);
}

// ---------------- elementwise fp32 -> bf16 ----------------
__global__ __launch_bounds__(256) void k_cvt(const float* __restrict__ in,
                                             unsigned short* __restrict__ out) {
  size_t i = ((size_t)blockIdx.x * 256 + threadIdx.x) * 8;
  float4 a = *(const float4*)(in + i);
  float4 b = *(const float4*)(in + i + 4);
  u16x8 o;
  o[0] = f2bf(a.x); o[1] = f2bf(a.y); o[2] = f2bf(a.z); o[3] = f2bf(a.w);
  o[4] = f2bf(b.x); o[5] = f2bf(b.y); o[6] = f2bf(b.z); o[7] = f2bf(b.w);
  *(u16x8*)(out + i) = o;
}

// ---------------- transpose fp32 [R][C] -> bf16 [C][R] ----------------
__global__ __launch_bounds__(256) void k_tr_f32bf16(const float* __restrict__ in,
                                                    unsigned short* __restrict__ out,
                                                    int R, int C) {
  __shared__ unsigned short t[64][72];
  int r0 = blockIdx.y * 64, c0 = blockIdx.x * 64;
  int tid = threadIdx.x;
  int rr = tid >> 4, cc = (tid & 15) * 4;
#pragma unroll
  for (int p = 0; p < 4; p++) {
    int r = p * 16 + rr;
    float4 v = *(const float4*)(in + (size_t)(r0 + r) * C + c0 + cc);
    t[r][cc + 0] = f2bf(v.x); t[r][cc + 1] = f2bf(v.y);
    t[r][cc + 2] = f2bf(v.z); t[r][cc + 3] = f2bf(v.w);
  }
  __syncthreads();
#pragma unroll
  for (int p = 0; p < 4; p++) {
    int c = p * 16 + rr;  // output row = input col
    u16x4 v;
    v[0] = t[cc + 0][c]; v[1] = t[cc + 1][c];
    v[2] = t[cc + 2][c]; v[3] = t[cc + 3][c];
    *(u16x4*)(out + (size_t)(c0 + c) * R + r0 + cc) = v;
  }
}

// ---------------- per-(b,h) transpose bf16 [T][64] -> [64][T] ----------------
__global__ __launch_bounds__(256) void k_tr_v(const unsigned short* __restrict__ v,
                                              unsigned short* __restrict__ vt) {
  __shared__ unsigned short s[64][72];
  int bh = blockIdx.y, t0 = blockIdx.x * 64;
  const unsigned short* in = v + (size_t)bh * SEQ * HD + (size_t)t0 * HD;
  unsigned short* out = vt + (size_t)bh * HD * SEQ + t0;
  int tid = threadIdx.x;
  int rr = tid >> 3, cc = (tid & 7) * 8;
#pragma unroll
  for (int p = 0; p < 2; p++) {
    int r = p * 32 + rr;
    u16x8 x = *(const u16x8*)(in + r * HD + cc);
#pragma unroll
    for (int j = 0; j < 8; j++) s[r][cc + j] = x[j];
  }
  __syncthreads();
#pragma unroll
  for (int p = 0; p < 2; p++) {
    int d = p * 32 + rr;
    u16x8 o;
#pragma unroll
    for (int j = 0; j < 8; j++) o[j] = s[cc + j][d];
    *(u16x8*)(out + (size_t)d * SEQ + cc) = o;
  }
}

// ---------------- GEMM  C[M][N] = A[M][K] * Bt[N][K]^T + bias ----------------
// EPI==0: scatter into Q/K/V [B,H,T,64] bf16 regions (Cout = q base)
// EPI==1: plain fp32 [M][N] out
template <int EPI>
__global__ __launch_bounds__(256) void k_gemm_bt(const unsigned short* __restrict__ A,
                                                 const unsigned short* __restrict__ Bt,
                                                 const float* __restrict__ bias,
                                                 void* __restrict__ Cout,
                                                 int M, int N, int K) {
  __shared__ unsigned short Al[128 * 64];
  __shared__ unsigned short Bl[128 * 64];
  const int tid = threadIdx.x, lane = tid & 63, w = tid >> 6;
  const int wm = w >> 1, wn = w & 1;
  const int m0 = blockIdx.y * 128, n0 = blockIdx.x * 128;
  const f32x4 fzero = {0.f, 0.f, 0.f, 0.f};

  f32x4 acc[4][4];
#pragma unroll
  for (int m = 0; m < 4; m++)
#pragma unroll
    for (int n = 0; n < 4; n++) acc[m][n] = fzero;

  for (int k0 = 0; k0 < K; k0 += 64) {
    __syncthreads();
#pragma unroll
    for (int i = 0; i < 4; i++) {
      int row = w * 32 + i * 8 + (lane >> 3);
      int ch = (lane & 7) ^ (row & 7);  // pre-swizzled global source (rule #21)
      gld16(&Al[(w * 32 + i * 8) * 64], A + (size_t)(m0 + row) * K + k0 + ch * 8);
      gld16(&Bl[(w * 32 + i * 8) * 64], Bt + (size_t)(n0 + row) * K + k0 + ch * 8);
    }
    __syncthreads();
#pragma unroll
    for (int ks = 0; ks < 2; ks++) {
      bf16x8 af[4], bfr[4];
#pragma unroll
      for (int m = 0; m < 4; m++) {
        int row = wm * 64 + m * 16 + (lane & 15);
        int ch = (ks * 4 + (lane >> 4)) ^ (row & 7);
        af[m] = *(const bf16x8*)&Al[row * 64 + ch * 8];
      }
#pragma unroll
      for (int n = 0; n < 4; n++) {
        int row = wn * 64 + n * 16 + (lane & 15);
        int ch = (ks * 4 + (lane >> 4)) ^ (row & 7);
        bfr[n] = *(const bf16x8*)&Bl[row * 64 + ch * 8];
      }
#pragma unroll
      for (int m = 0; m < 4; m++)
#pragma unroll
        for (int n = 0; n < 4; n++)
          acc[m][n] = __builtin_amdgcn_mfma_f32_16x16x32_bf16(af[m], bfr[n], acc[m][n], 0, 0, 0);
    }
  }

#pragma unroll
  for (int m = 0; m < 4; m++) {
#pragma unroll
    for (int n = 0; n < 4; n++) {
      int col = n0 + wn * 64 + n * 16 + (lane & 15);
      float bv = bias[col];
#pragma unroll
      for (int r = 0; r < 4; r++) {
        int row = m0 + wm * 64 + m * 16 + (lane >> 4) * 4 + r;
        float val = acc[m][n][r] + bv;
        if (EPI == 1) {
          ((float*)Cout)[(size_t)row * N + col] = val;
        } else {
          unsigned short* dst = (unsigned short*)Cout;
          int reg = col >> 10, nn = col & 1023;
          int h = nn >> 6, d = nn & 63;
          int b = row >> 11, t = row & 2047;
          size_t idx = (size_t)reg * QKV_REGION +
                       ((size_t)(b * NHEAD + h) * SEQ + t) * HD + d;
          dst[idx] = f2bf(val);
        }
      }
    }
  }
}

// ---------------- causal flash attention ----------------
// Q,K: [B,H,T,64] bf16; Vt: [B,H,64,T] bf16; O: [B,T,H*64] bf16
__global__ __launch_bounds__(256) void k_attn(const unsigned short* __restrict__ Q,
                                              const unsigned short* __restrict__ K,
                                              const unsigned short* __restrict__ Vt,
                                              unsigned short* __restrict__ O) {
  __shared__ unsigned short qp[128 * 64];  // Q tile, then reused as per-wave P
  __shared__ unsigned short kl[64 * 64];
  __shared__ unsigned short vl[64 * 64];
  const int tid = threadIdx.x, lane = tid & 63, w = tid >> 6;
  const int qt = blockIdx.x, bh = blockIdx.y;
  const unsigned short* Qb = Q + (size_t)bh * SEQ * HD;
  const unsigned short* Kb = K + (size_t)bh * SEQ * HD;
  const unsigned short* Vb = Vt + (size_t)bh * HD * SEQ;
  const f32x4 fzero = {0.f, 0.f, 0.f, 0.f};

  // stage Q tile (128 x 64), swizzled
#pragma unroll
  for (int i = 0; i < 4; i++) {
    int row = w * 32 + i * 8 + (lane >> 3);
    int ch = (lane & 7) ^ (row & 7);
    gld16(&qp[(w * 32 + i * 8) * 64], Qb + (size_t)(qt * 128 + row) * HD + ch * 8);
  }
  __syncthreads();

  // Q fragments to registers (wave-private rows w*32..w*32+31)
  bf16x8 qf[2][2];
#pragma unroll
  for (int mf = 0; mf < 2; mf++)
#pragma unroll
    for (int ks = 0; ks < 2; ks++) {
      int row = w * 32 + mf * 16 + (lane & 15);
      int ch = (ks * 4 + (lane >> 4)) ^ (row & 7);
      qf[mf][ks] = *(const bf16x8*)&qp[row * 64 + ch * 8];
    }

  f32x4 oacc[2][4];
  float mrun[2][4], lpart[2][4];
#pragma unroll
  for (int mf = 0; mf < 2; mf++) {
#pragma unroll
    for (int nd = 0; nd < 4; nd++) oacc[mf][nd] = fzero;
#pragma unroll
    for (int r = 0; r < 4; r++) { mrun[mf][r] = -__builtin_inff(); lpart[mf][r] = 0.f; }
  }

  const float SC = 0.18033688011112042f;  // (1/8) * log2(e)
  const int ntiles = 2 * qt + 2;
  for (int kt = 0; kt < ntiles; kt++) {
    const int kb = kt * 64;
    __syncthreads();
#pragma unroll
    for (int i = 0; i < 2; i++) {
      int row = w * 16 + i * 8 + (lane >> 3);
      int ch = (lane & 7) ^ (row & 7);
      gld16(&kl[(w * 16 + i * 8) * 64], Kb + (size_t)(kb + row) * HD + ch * 8);
      gld16(&vl[(w * 16 + i * 8) * 64], Vb + (size_t)row * SEQ + kb + ch * 8);
    }
    __syncthreads();

    // S = Q K^T for this wave's 32 q-rows
    f32x4 sacc[2][4];
#pragma unroll
    for (int mf = 0; mf < 2; mf++)
#pragma unroll
      for (int nk = 0; nk < 4; nk++) sacc[mf][nk] = fzero;

#pragma unroll
    for (int ks = 0; ks < 2; ks++) {
      bf16x8 kf[4];
#pragma unroll
      for (int nk = 0; nk < 4; nk++) {
        int row = nk * 16 + (lane & 15);
        int ch = (ks * 4 + (lane >> 4)) ^ (row & 7);
        kf[nk] = *(const bf16x8*)&kl[row * 64 + ch * 8];
      }
#pragma unroll
      for (int mf = 0; mf < 2; mf++)
#pragma unroll
        for (int nk = 0; nk < 4; nk++)
          sacc[mf][nk] = __builtin_amdgcn_mfma_f32_16x16x32_bf16(qf[mf][ks], kf[nk], sacc[mf][nk], 0, 0, 0);
    }

    const bool need_mask = (kt >= 2 * qt);
#pragma unroll
    for (int mf = 0; mf < 2; mf++) {
      float p[4][4];
      float rmax[4];
#pragma unroll
      for (int r = 0; r < 4; r++) rmax[r] = -__builtin_inff();
#pragma unroll
      for (int nk = 0; nk < 4; nk++)
#pragma unroll
        for (int r = 0; r < 4; r++) {
          float s = sacc[mf][nk][r] * SC;
          if (need_mask) {
            int qrow = qt * 128 + w * 32 + mf * 16 + (lane >> 4) * 4 + r;
            int kv = kb + nk * 16 + (lane & 15);
            if (kv > qrow) s = -__builtin_inff();
          }
          p[nk][r] = s;
          rmax[r] = fmaxf(rmax[r], s);
        }
#pragma unroll
      for (int r = 0; r < 4; r++) {
        rmax[r] = fmaxf(rmax[r], __shfl_xor(rmax[r], 1));
        rmax[r] = fmaxf(rmax[r], __shfl_xor(rmax[r], 2));
        rmax[r] = fmaxf(rmax[r], __shfl_xor(rmax[r], 4));
        rmax[r] = fmaxf(rmax[r], __shfl_xor(rmax[r], 8));
        float mnew = fmaxf(mrun[mf][r], rmax[r]);
        float fac = exp2f(mrun[mf][r] - mnew);
        mrun[mf][r] = mnew;
        float rs = 0.f;
#pragma unroll
        for (int nk = 0; nk < 4; nk++) {
          float pv = exp2f(p[nk][r] - mnew);
          p[nk][r] = pv;
          rs += pv;
        }
        lpart[mf][r] = lpart[mf][r] * fac + rs;
#pragma unroll
        for (int nd = 0; nd < 4; nd++) oacc[mf][nd][r] *= fac;
      }
      // write P (bf16) to wave-private LDS region, swizzled
#pragma unroll
      for (int nk = 0; nk < 4; nk++)
#pragma unroll
        for (int r = 0; r < 4; r++) {
          int prow = mf * 16 + (lane >> 4) * 4 + r;
          int pcol = nk * 16 + (lane & 15);
          int ch = (pcol >> 3) ^ (prow & 7);
          qp[(w * 32 + prow) * 64 + ch * 8 + (pcol & 7)] = f2bf(p[nk][r]);
        }
    }

    // O += P @ V   (Vt tile rows are d, cols kv -> B^T layout)
#pragma unroll
    for (int ks = 0; ks < 2; ks++) {
      bf16x8 vf[4], pa[2];
#pragma unroll
      for (int nd = 0; nd < 4; nd++) {
        int row = nd * 16 + (lane & 15);
        int ch = (ks * 4 + (lane >> 4)) ^ (row & 7);
        vf[nd] = *(const bf16x8*)&vl[row * 64 + ch * 8];
      }
#pragma unroll
      for (int mf = 0; mf < 2; mf++) {
        int prow = mf * 16 + (lane & 15);
        int ch = (ks * 4 + (lane >> 4)) ^ (prow & 7);
        pa[mf] = *(const bf16x8*)&qp[(w * 32 + prow) * 64 + ch * 8];
      }
#pragma unroll
      for (int mf = 0; mf < 2; mf++)
#pragma unroll
        for (int nd = 0; nd < 4; nd++)
          oacc[mf][nd] = __builtin_amdgcn_mfma_f32_16x16x32_bf16(pa[mf], vf[nd], oacc[mf][nd], 0, 0, 0);
    }
  }

  // normalize + write O as [B,T,H*64]
  const int b = bh >> 4, h = bh & 15;
#pragma unroll
  for (int mf = 0; mf < 2; mf++) {
    float linv[4];
#pragma unroll
    for (int r = 0; r < 4; r++) {
      float l = lpart[mf][r];
      l += __shfl_xor(l, 1);
      l += __shfl_xor(l, 2);
      l += __shfl_xor(l, 4);
      l += __shfl_xor(l, 8);
      linv[r] = 1.f / l;
    }
#pragma unroll
    for (int nd = 0; nd < 4; nd++) {
      int d = nd * 16 + (lane & 15);
#pragma unroll
      for (int r = 0; r < 4; r++) {
        int t = qt * 128 + w * 32 + mf * 16 + (lane >> 4) * 4 + r;
        float val = oacc[mf][nd][r] * linv[r];
        O[((size_t)(b * SEQ + t)) * DIM + h * HD + d] = f2bf(val);
      }
    }
  }
}

// ---------------- launch ----------------
extern "C" void kernel_launch(void* const* d_in, const int* in_sizes, int n_in,
                              void* d_out, int out_size, void* d_ws, size_t ws_size,
                              hipStream_t stream) {
  const float* x     = (const float*)d_in[0];
  const float* Wqkv  = (const float*)d_in[1];
  const float* bqkv  = (const float*)d_in[2];
  const float* Wproj = (const float*)d_in[3];
  const float* bproj = (const float*)d_in[4];
  // d_in[5] = causal mask (structure known; not read)
  float* out = (float*)d_out;

  unsigned short* ws     = (unsigned short*)d_ws;
  unsigned short* xb_vt  = ws;                  // 4,194,304 elems: x_bf16, later V^T
  unsigned short* wqkvt  = xb_vt + 4194304;     // 3,145,728: W_qkv^T bf16
  unsigned short* wprojt = wqkvt + 3145728;     // 1,048,576: W_proj^T bf16
  unsigned short* q      = wprojt + 1048576;    // 4,194,304
  unsigned short* k      = q + 4194304;         // 4,194,304
  unsigned short* v_o    = k + 4194304;         // 4,194,304: V, later attn O
  // total 40 MB of d_ws

  k_cvt<<<2048, 256, 0, stream>>>(x, xb_vt);
  k_tr_f32bf16<<<dim3(48, 16), 256, 0, stream>>>(Wqkv, wqkvt, 1024, 3072);
  k_tr_f32bf16<<<dim3(16, 16), 256, 0, stream>>>(Wproj, wprojt, 1024, 1024);
  k_gemm_bt<0><<<dim3(24, 32), 256, 0, stream>>>(xb_vt, wqkvt, bqkv, q, NTOK, 3072, DIM);
  k_tr_v<<<dim3(32, 32), 256, 0, stream>>>(v_o, xb_vt);
  k_attn<<<dim3(16, 32), 256, 0, stream>>>(q, k, xb_vt, v_o);
  k_gemm_bt<1><<<dim3(8, 32), 256, 0, stream>>>(v_o, wprojt, bproj, out, NTOK, DIM, DIM);
}

// Round 2
// 154.916 us; speedup vs baseline: 1.6656x; 1.6656x over previous
//
#include <hip/hip_runtime.h>
#include <stdint.h>

#define DIM   1024
#define NHEAD 16
#define HD    64
#define SEQ   2048
#define NTOK  4096
#define QKV_REGION (NTOK * DIM)   // 4194304 elements per Q/K/V region

typedef short          bf16x8 __attribute__((ext_vector_type(8)));
typedef float          f32x4  __attribute__((ext_vector_type(4)));
typedef unsigned short u16x8  __attribute__((ext_vector_type(8)));
typedef unsigned short u16x4  __attribute__((ext_vector_type(4)));

__device__ __forceinline__ unsigned short f2bf(float f) {
  union { float f; unsigned u; } x; x.f = f;
  unsigned r = x.u + 0x7FFFu + ((x.u >> 16) & 1u);  // RNE
  return (unsigned short)(r >> 16);
}

__device__ __forceinline__ void gld16(void* lds, const void* g) {
  __builtin_amdgcn_global_load_lds(
      (const __attribute__((address_space(1))) unsigned int*)g,
      (__attribute__((address_space(3))) unsigned int*)lds, 16, 0, 0);
}

// ---------------- elementwise fp32 -> bf16 ----------------
__global__ __launch_bounds__(256) void k_cvt(const float* __restrict__ in,
                                             unsigned short* __restrict__ out) {
  size_t i = ((size_t)blockIdx.x * 256 + threadIdx.x) * 8;
  float4 a = *(const float4*)(in + i);
  float4 b = *(const float4*)(in + i + 4);
  u16x8 o;
  o[0] = f2bf(a.x); o[1] = f2bf(a.y); o[2] = f2bf(a.z); o[3] = f2bf(a.w);
  o[4] = f2bf(b.x); o[5] = f2bf(b.y); o[6] = f2bf(b.z); o[7] = f2bf(b.w);
  *(u16x8*)(out + i) = o;
}

// ---------------- transpose fp32 [R][C] -> bf16 [C][R] ----------------
__global__ __launch_bounds__(256) void k_tr_f32bf16(const float* __restrict__ in,
                                                    unsigned short* __restrict__ out,
                                                    int R, int C) {
  __shared__ unsigned short t[64][72];
  int r0 = blockIdx.y * 64, c0 = blockIdx.x * 64;
  int tid = threadIdx.x;
  int rr = tid >> 4, cc = (tid & 15) * 4;
#pragma unroll
  for (int p = 0; p < 4; p++) {
    int r = p * 16 + rr;
    float4 v = *(const float4*)(in + (size_t)(r0 + r) * C + c0 + cc);
    t[r][cc + 0] = f2bf(v.x); t[r][cc + 1] = f2bf(v.y);
    t[r][cc + 2] = f2bf(v.z); t[r][cc + 3] = f2bf(v.w);
  }
  __syncthreads();
#pragma unroll
  for (int p = 0; p < 4; p++) {
    int c = p * 16 + rr;  // output row = input col
    u16x4 v;
    v[0] = t[cc + 0][c]; v[1] = t[cc + 1][c];
    v[2] = t[cc + 2][c]; v[3] = t[cc + 3][c];
    *(u16x4*)(out + (size_t)(c0 + c) * R + r0 + cc) = v;
  }
}

// ---------------- per-(b,h) transpose bf16 [T][64] -> [64][T] ----------------
__global__ __launch_bounds__(256) void k_tr_v(const unsigned short* __restrict__ v,
                                              unsigned short* __restrict__ vt) {
  __shared__ unsigned short s[64][72];
  int bh = blockIdx.y, t0 = blockIdx.x * 64;
  const unsigned short* in = v + (size_t)bh * SEQ * HD + (size_t)t0 * HD;
  unsigned short* out = vt + (size_t)bh * HD * SEQ + t0;
  int tid = threadIdx.x;
  int rr = tid >> 3, cc = (tid & 7) * 8;
#pragma unroll
  for (int p = 0; p < 2; p++) {
    int r = p * 32 + rr;
    u16x8 x = *(const u16x8*)(in + r * HD + cc);
#pragma unroll
    for (int j = 0; j < 8; j++) s[r][cc + j] = x[j];
  }
  __syncthreads();
#pragma unroll
  for (int p = 0; p < 2; p++) {
    int d = p * 32 + rr;
    u16x8 o;
#pragma unroll
    for (int j = 0; j < 8; j++) o[j] = s[cc + j][d];
    *(u16x8*)(out + (size_t)d * SEQ + cc) = o;
  }
}

// ---------------- GEMM  C[M][N] = A[M][K] * Bt[N][K]^T + bias ----------------
template <int EPI>
__global__ __launch_bounds__(256) void k_gemm_bt(const unsigned short* __restrict__ A,
                                                 const unsigned short* __restrict__ Bt,
                                                 const float* __restrict__ bias,
                                                 void* __restrict__ Cout,
                                                 int M, int N, int K) {
  __shared__ unsigned short Al[128 * 64];
  __shared__ unsigned short Bl[128 * 64];
  const int tid = threadIdx.x, lane = tid & 63, w = tid >> 6;
  const int wm = w >> 1, wn = w & 1;
  const int m0 = blockIdx.y * 128, n0 = blockIdx.x * 128;
  const f32x4 fzero = {0.f, 0.f, 0.f, 0.f};

  f32x4 acc[4][4];
#pragma unroll
  for (int m = 0; m < 4; m++)
#pragma unroll
    for (int n = 0; n < 4; n++) acc[m][n] = fzero;

  for (int k0 = 0; k0 < K; k0 += 64) {
    __syncthreads();
#pragma unroll
    for (int i = 0; i < 4; i++) {
      int row = w * 32 + i * 8 + (lane >> 3);
      int ch = (lane & 7) ^ (row & 7);  // pre-swizzled global source
      gld16(&Al[(w * 32 + i * 8) * 64], A + (size_t)(m0 + row) * K + k0 + ch * 8);
      gld16(&Bl[(w * 32 + i * 8) * 64], Bt + (size_t)(n0 + row) * K + k0 + ch * 8);
    }
    __syncthreads();
#pragma unroll
    for (int ks = 0; ks < 2; ks++) {
      bf16x8 af[4], bfr[4];
#pragma unroll
      for (int m = 0; m < 4; m++) {
        int row = wm * 64 + m * 16 + (lane & 15);
        int ch = (ks * 4 + (lane >> 4)) ^ (row & 7);
        af[m] = *(const bf16x8*)&Al[row * 64 + ch * 8];
      }
#pragma unroll
      for (int n = 0; n < 4; n++) {
        int row = wn * 64 + n * 16 + (lane & 15);
        int ch = (ks * 4 + (lane >> 4)) ^ (row & 7);
        bfr[n] = *(const bf16x8*)&Bl[row * 64 + ch * 8];
      }
#pragma unroll
      for (int m = 0; m < 4; m++)
#pragma unroll
        for (int n = 0; n < 4; n++)
          acc[m][n] = __builtin_amdgcn_mfma_f32_16x16x32_bf16(af[m], bfr[n], acc[m][n], 0, 0, 0);
    }
  }

#pragma unroll
  for (int m = 0; m < 4; m++) {
#pragma unroll
    for (int n = 0; n < 4; n++) {
      int col = n0 + wn * 64 + n * 16 + (lane & 15);
      float bv = bias[col];
#pragma unroll
      for (int r = 0; r < 4; r++) {
        int row = m0 + wm * 64 + m * 16 + (lane >> 4) * 4 + r;
        float val = acc[m][n][r] + bv;
        if (EPI == 1) {
          ((float*)Cout)[(size_t)row * N + col] = val;
        } else {
          unsigned short* dst = (unsigned short*)Cout;
          int reg = col >> 10, nn = col & 1023;
          int h = nn >> 6, d = nn & 63;
          int b = row >> 11, t = row & 2047;
          size_t idx = (size_t)reg * QKV_REGION +
                       ((size_t)(b * NHEAD + h) * SEQ + t) * HD + d;
          dst[idx] = f2bf(val);
        }
      }
    }
  }
}

// ---------------- causal flash attention (QBLK=64, 4 waves x 16 rows, dbuf KV) ----
// Q,K: [B,H,T,64] bf16; Vt: [B,H,64,T] bf16; O: [B,T,H*64] bf16
__global__ __launch_bounds__(256, 4) void k_attn(const unsigned short* __restrict__ Q,
                                                 const unsigned short* __restrict__ K,
                                                 const unsigned short* __restrict__ Vt,
                                                 unsigned short* __restrict__ O) {
  __shared__ unsigned short kl[2][64 * 64];
  __shared__ unsigned short vl[2][64 * 64];
  __shared__ unsigned short pl[4][16 * 64];
  const int tid = threadIdx.x, lane = tid & 63, w = tid >> 6;
  const int id = blockIdx.x;
  const int bh = id & 31;
  const int qt = 31 - (id >> 5);   // heavy blocks first
  const unsigned short* Qb = Q + (size_t)bh * SEQ * HD;
  const unsigned short* Kb = K + (size_t)bh * SEQ * HD;
  const unsigned short* Vb = Vt + (size_t)bh * HD * SEQ;
  const f32x4 fzero = {0.f, 0.f, 0.f, 0.f};

  // Q fragments straight from global (no LDS): wave w owns q-rows qt*64+w*16..+15
  const int qrow = qt * 64 + w * 16 + (lane & 15);
  bf16x8 qf[2];
#pragma unroll
  for (int ks = 0; ks < 2; ks++)
    qf[ks] = *(const bf16x8*)(Qb + (size_t)qrow * HD + (ks * 4 + (lane >> 4)) * 8);

  f32x4 oacc[4];
  float mrun[4], lpart[4];
#pragma unroll
  for (int nd = 0; nd < 4; nd++) oacc[nd] = fzero;
#pragma unroll
  for (int r = 0; r < 4; r++) { mrun[r] = -__builtin_inff(); lpart[r] = 0.f; }

  const float SC = 0.18033688011112042f;  // (1/8) * log2(e)
  const int ntiles = qt + 1;

#define STAGE(KT, BUF)                                                          \
  {                                                                             \
    const int kb_ = (KT) * 64;                                                  \
    _Pragma("unroll")                                                           \
    for (int i = 0; i < 2; i++) {                                               \
      int row = w * 16 + i * 8 + (lane >> 3);                                   \
      int ch = (lane & 7) ^ (row & 7);                                          \
      gld16(&kl[BUF][(w * 16 + i * 8) * 64], Kb + (size_t)(kb_ + row) * HD + ch * 8); \
      gld16(&vl[BUF][(w * 16 + i * 8) * 64], Vb + (size_t)row * SEQ + kb_ + ch * 8);  \
    }                                                                           \
  }

  STAGE(0, 0);
  __syncthreads();
  int cur = 0;

  for (int kt = 0; kt < ntiles; kt++) {
    if (kt + 1 < ntiles) STAGE(kt + 1, cur ^ 1);   // prefetch flies during compute

    // ---- S = Q K^T for this wave's 16 q-rows x 64 kv ----
    f32x4 sacc[4];
#pragma unroll
    for (int nk = 0; nk < 4; nk++) sacc[nk] = fzero;
#pragma unroll
    for (int ks = 0; ks < 2; ks++) {
      bf16x8 kf[4];
#pragma unroll
      for (int nk = 0; nk < 4; nk++) {
        int row = nk * 16 + (lane & 15);
        int ch = (ks * 4 + (lane >> 4)) ^ (row & 7);
        kf[nk] = *(const bf16x8*)&kl[cur][row * 64 + ch * 8];
      }
#pragma unroll
      for (int nk = 0; nk < 4; nk++)
        sacc[nk] = __builtin_amdgcn_mfma_f32_16x16x32_bf16(qf[ks], kf[nk], sacc[nk], 0, 0, 0);
    }

    // ---- online softmax ----
    const bool need_mask = (kt == qt);
    float p[4][4];
    float rmax[4];
#pragma unroll
    for (int r = 0; r < 4; r++) rmax[r] = -__builtin_inff();
#pragma unroll
    for (int nk = 0; nk < 4; nk++)
#pragma unroll
      for (int r = 0; r < 4; r++) {
        float s = sacc[nk][r] * SC;
        if (need_mask) {
          int qr = qt * 64 + w * 16 + (lane >> 4) * 4 + r;
          int kv = kt * 64 + nk * 16 + (lane & 15);
          if (kv > qr) s = -__builtin_inff();
        }
        p[nk][r] = s;
        rmax[r] = fmaxf(rmax[r], s);
      }
#pragma unroll
    for (int r = 0; r < 4; r++) {
      rmax[r] = fmaxf(rmax[r], __shfl_xor(rmax[r], 1));
      rmax[r] = fmaxf(rmax[r], __shfl_xor(rmax[r], 2));
      rmax[r] = fmaxf(rmax[r], __shfl_xor(rmax[r], 4));
      rmax[r] = fmaxf(rmax[r], __shfl_xor(rmax[r], 8));
      float mnew = fmaxf(mrun[r], rmax[r]);
      float fac = exp2f(mrun[r] - mnew);
      mrun[r] = mnew;
      float rs = 0.f;
#pragma unroll
      for (int nk = 0; nk < 4; nk++) {
        float pv = exp2f(p[nk][r] - mnew);
        p[nk][r] = pv;
        rs += pv;
      }
      lpart[r] = lpart[r] * fac + rs;
#pragma unroll
      for (int nd = 0; nd < 4; nd++) oacc[nd][r] *= fac;
    }

    // ---- P -> wave-private LDS (bf16, swizzled); DS ops are in-order per wave ----
#pragma unroll
    for (int nk = 0; nk < 4; nk++)
#pragma unroll
      for (int r = 0; r < 4; r++) {
        int prow = (lane >> 4) * 4 + r;
        int pcol = nk * 16 + (lane & 15);
        int ch = (pcol >> 3) ^ (prow & 7);
        pl[w][prow * 64 + ch * 8 + (pcol & 7)] = f2bf(p[nk][r]);
      }

    // ---- O += P @ V ----
#pragma unroll
    for (int ks = 0; ks < 2; ks++) {
      bf16x8 vf[4], pa;
#pragma unroll
      for (int nd = 0; nd < 4; nd++) {
        int row = nd * 16 + (lane & 15);
        int ch = (ks * 4 + (lane >> 4)) ^ (row & 7);
        vf[nd] = *(const bf16x8*)&vl[cur][row * 64 + ch * 8];
      }
      {
        int prow = lane & 15;
        int ch = (ks * 4 + (lane >> 4)) ^ (prow & 7);
        pa = *(const bf16x8*)&pl[w][prow * 64 + ch * 8];
      }
#pragma unroll
      for (int nd = 0; nd < 4; nd++)
        oacc[nd] = __builtin_amdgcn_mfma_f32_16x16x32_bf16(pa, vf[nd], oacc[nd], 0, 0, 0);
    }

    __syncthreads();   // drains prefetch (mostly landed) + publishes buffers; 1/tile
    cur ^= 1;
  }
#undef STAGE

  // ---- normalize + write O as [B,T,H*64] ----
  const int b = bh >> 4, h = bh & 15;
  float linv[4];
#pragma unroll
  for (int r = 0; r < 4; r++) {
    float l = lpart[r];
    l += __shfl_xor(l, 1);
    l += __shfl_xor(l, 2);
    l += __shfl_xor(l, 4);
    l += __shfl_xor(l, 8);
    linv[r] = 1.f / l;
  }
#pragma unroll
  for (int nd = 0; nd < 4; nd++) {
    int d = nd * 16 + (lane & 15);
#pragma unroll
    for (int r = 0; r < 4; r++) {
      int t = qt * 64 + w * 16 + (lane >> 4) * 4 + r;
      float val = oacc[nd][r] * linv[r];
      O[((size_t)(b * SEQ + t)) * DIM + h * HD + d] = f2bf(val);
    }
  }
}

// ---------------- launch ----------------
extern "C" void kernel_launch(void* const* d_in, const int* in_sizes, int n_in,
                              void* d_out, int out_size, void* d_ws, size_t ws_size,
                              hipStream_t stream) {
  const float* x     = (const float*)d_in[0];
  const float* Wqkv  = (const float*)d_in[1];
  const float* bqkv  = (const float*)d_in[2];
  const float* Wproj = (const float*)d_in[3];
  const float* bproj = (const float*)d_in[4];
  float* out = (float*)d_out;

  unsigned short* ws     = (unsigned short*)d_ws;
  unsigned short* xb_vt  = ws;                  // 4,194,304 elems: x_bf16, later V^T
  unsigned short* wqkvt  = xb_vt + 4194304;     // 3,145,728: W_qkv^T bf16
  unsigned short* wprojt = wqkvt + 3145728;     // 1,048,576: W_proj^T bf16
  unsigned short* q      = wprojt + 1048576;    // 4,194,304
  unsigned short* k      = q + 4194304;         // 4,194,304
  unsigned short* v_o    = k + 4194304;         // 4,194,304: V, later attn O
  // total 40 MB of d_ws

  k_cvt<<<2048, 256, 0, stream>>>(x, xb_vt);
  k_tr_f32bf16<<<dim3(48, 16), 256, 0, stream>>>(Wqkv, wqkvt, 1024, 3072);
  k_tr_f32bf16<<<dim3(16, 16), 256, 0, stream>>>(Wproj, wprojt, 1024, 1024);
  k_gemm_bt<0><<<dim3(24, 32), 256, 0, stream>>>(xb_vt, wqkvt, bqkv, q, NTOK, 3072, DIM);
  k_tr_v<<<dim3(32, 32), 256, 0, stream>>>(v_o, xb_vt);
  k_attn<<<dim3(1024), 256, 0, stream>>>(q, k, xb_vt, v_o);
  k_gemm_bt<1><<<dim3(8, 32), 256, 0, stream>>>(v_o, wprojt, bproj, out, NTOK, DIM, DIM);
}

// Round 3
// 144.693 us; speedup vs baseline: 1.7833x; 1.0706x over previous
//
#include <hip/hip_runtime.h>
#include <stdint.h>

#define DIM   1024
#define NHEAD 16
#define HD    64
#define SEQ   2048
#define NTOK  4096
#define QKV_REGION (NTOK * DIM)   // 4194304 elements per Q/K/V region

typedef short          bf16x8 __attribute__((ext_vector_type(8)));
typedef float          f32x4  __attribute__((ext_vector_type(4)));
typedef unsigned short u16x8  __attribute__((ext_vector_type(8)));
typedef unsigned short u16x4  __attribute__((ext_vector_type(4)));

__device__ __forceinline__ unsigned short f2bf(float f) {
  union { float f; unsigned u; } x; x.f = f;
  unsigned r = x.u + 0x7FFFu + ((x.u >> 16) & 1u);  // RNE
  return (unsigned short)(r >> 16);
}

__device__ __forceinline__ void gld16(void* lds, const void* g) {
  __builtin_amdgcn_global_load_lds(
      (const __attribute__((address_space(1))) unsigned int*)g,
      (__attribute__((address_space(3))) unsigned int*)lds, 16, 0, 0);
}

// ---------------- elementwise fp32 -> bf16 ----------------
__global__ __launch_bounds__(256) void k_cvt(const float* __restrict__ in,
                                             unsigned short* __restrict__ out) {
  size_t i = ((size_t)blockIdx.x * 256 + threadIdx.x) * 8;
  float4 a = *(const float4*)(in + i);
  float4 b = *(const float4*)(in + i + 4);
  u16x8 o;
  o[0] = f2bf(a.x); o[1] = f2bf(a.y); o[2] = f2bf(a.z); o[3] = f2bf(a.w);
  o[4] = f2bf(b.x); o[5] = f2bf(b.y); o[6] = f2bf(b.z); o[7] = f2bf(b.w);
  *(u16x8*)(out + i) = o;
}

// ---------------- transpose fp32 [R][C] -> bf16 [C][R] ----------------
__global__ __launch_bounds__(256) void k_tr_f32bf16(const float* __restrict__ in,
                                                    unsigned short* __restrict__ out,
                                                    int R, int C) {
  __shared__ unsigned short t[64][72];
  int r0 = blockIdx.y * 64, c0 = blockIdx.x * 64;
  int tid = threadIdx.x;
  int rr = tid >> 4, cc = (tid & 15) * 4;
#pragma unroll
  for (int p = 0; p < 4; p++) {
    int r = p * 16 + rr;
    float4 v = *(const float4*)(in + (size_t)(r0 + r) * C + c0 + cc);
    t[r][cc + 0] = f2bf(v.x); t[r][cc + 1] = f2bf(v.y);
    t[r][cc + 2] = f2bf(v.z); t[r][cc + 3] = f2bf(v.w);
  }
  __syncthreads();
#pragma unroll
  for (int p = 0; p < 4; p++) {
    int c = p * 16 + rr;  // output row = input col
    u16x4 v;
    v[0] = t[cc + 0][c]; v[1] = t[cc + 1][c];
    v[2] = t[cc + 2][c]; v[3] = t[cc + 3][c];
    *(u16x4*)(out + (size_t)(c0 + c) * R + r0 + cc) = v;
  }
}

// ---------------- per-(b,h) transpose bf16 [T][64] -> [64][T] ----------------
__global__ __launch_bounds__(256) void k_tr_v(const unsigned short* __restrict__ v,
                                              unsigned short* __restrict__ vt) {
  __shared__ unsigned short s[64][72];
  int bh = blockIdx.y, t0 = blockIdx.x * 64;
  const unsigned short* in = v + (size_t)bh * SEQ * HD + (size_t)t0 * HD;
  unsigned short* out = vt + (size_t)bh * HD * SEQ + t0;
  int tid = threadIdx.x;
  int rr = tid >> 3, cc = (tid & 7) * 8;
#pragma unroll
  for (int p = 0; p < 2; p++) {
    int r = p * 32 + rr;
    u16x8 x = *(const u16x8*)(in + r * HD + cc);
#pragma unroll
    for (int j = 0; j < 8; j++) s[r][cc + j] = x[j];
  }
  __syncthreads();
#pragma unroll
  for (int p = 0; p < 2; p++) {
    int d = p * 32 + rr;
    u16x8 o;
#pragma unroll
    for (int j = 0; j < 8; j++) o[j] = s[cc + j][d];
    *(u16x8*)(out + (size_t)d * SEQ + cc) = o;
  }
}

// ---------------- GEMM  C[M][N] = A[M][K] * Bt[N][K]^T + bias ----------------
// EPI==0: scatter into Q/K/V regions; Q gets pre-scaled by log2(e)/sqrt(HD)
// EPI==1: plain fp32 [M][N] out
template <int EPI>
__global__ __launch_bounds__(256) void k_gemm_bt(const unsigned short* __restrict__ A,
                                                 const unsigned short* __restrict__ Bt,
                                                 const float* __restrict__ bias,
                                                 void* __restrict__ Cout,
                                                 int M, int N, int K) {
  __shared__ unsigned short Al[128 * 64];
  __shared__ unsigned short Bl[128 * 64];
  const int tid = threadIdx.x, lane = tid & 63, w = tid >> 6;
  const int wm = w >> 1, wn = w & 1;
  const int m0 = blockIdx.y * 128, n0 = blockIdx.x * 128;
  const f32x4 fzero = {0.f, 0.f, 0.f, 0.f};

  f32x4 acc[4][4];
#pragma unroll
  for (int m = 0; m < 4; m++)
#pragma unroll
    for (int n = 0; n < 4; n++) acc[m][n] = fzero;

  for (int k0 = 0; k0 < K; k0 += 64) {
    __syncthreads();
#pragma unroll
    for (int i = 0; i < 4; i++) {
      int row = w * 32 + i * 8 + (lane >> 3);
      int ch = (lane & 7) ^ (row & 7);  // pre-swizzled global source
      gld16(&Al[(w * 32 + i * 8) * 64], A + (size_t)(m0 + row) * K + k0 + ch * 8);
      gld16(&Bl[(w * 32 + i * 8) * 64], Bt + (size_t)(n0 + row) * K + k0 + ch * 8);
    }
    __syncthreads();
#pragma unroll
    for (int ks = 0; ks < 2; ks++) {
      bf16x8 af[4], bfr[4];
#pragma unroll
      for (int m = 0; m < 4; m++) {
        int row = wm * 64 + m * 16 + (lane & 15);
        int ch = (ks * 4 + (lane >> 4)) ^ (row & 7);
        af[m] = *(const bf16x8*)&Al[row * 64 + ch * 8];
      }
#pragma unroll
      for (int n = 0; n < 4; n++) {
        int row = wn * 64 + n * 16 + (lane & 15);
        int ch = (ks * 4 + (lane >> 4)) ^ (row & 7);
        bfr[n] = *(const bf16x8*)&Bl[row * 64 + ch * 8];
      }
#pragma unroll
      for (int m = 0; m < 4; m++)
#pragma unroll
        for (int n = 0; n < 4; n++)
          acc[m][n] = __builtin_amdgcn_mfma_f32_16x16x32_bf16(af[m], bfr[n], acc[m][n], 0, 0, 0);
    }
  }

#pragma unroll
  for (int m = 0; m < 4; m++) {
#pragma unroll
    for (int n = 0; n < 4; n++) {
      int col = n0 + wn * 64 + n * 16 + (lane & 15);
      float bv = bias[col];
#pragma unroll
      for (int r = 0; r < 4; r++) {
        int row = m0 + wm * 64 + m * 16 + (lane >> 4) * 4 + r;
        float val = acc[m][n][r] + bv;
        if (EPI == 1) {
          ((float*)Cout)[(size_t)row * N + col] = val;
        } else {
          unsigned short* dst = (unsigned short*)Cout;
          int reg = col >> 10, nn = col & 1023;
          if (reg == 0) val *= 0.18033688011112042f;  // fold (1/sqrt(Dh))*log2(e) into Q
          int h = nn >> 6, d = nn & 63;
          int b = row >> 11, t = row & 2047;
          size_t idx = (size_t)reg * QKV_REGION +
                       ((size_t)(b * NHEAD + h) * SEQ + t) * HD + d;
          dst[idx] = f2bf(val);
        }
      }
    }
  }
}

// ---------------- causal flash attention: in-block split-KV ----------------
// 8 waves: waves 0-3 = low kv-half, waves 4-7 = high kv-half, same 64 q-rows.
// Q pre-scaled by log2(e)/8, so S is already in log2 domain.
// Q,K: [B,H,T,64] bf16; Vt: [B,H,64,T] bf16; O: [B,T,H*64] bf16
__global__ __launch_bounds__(512, 4) void k_attn(const unsigned short* __restrict__ Q,
                                                 const unsigned short* __restrict__ K,
                                                 const unsigned short* __restrict__ Vt,
                                                 unsigned short* __restrict__ O) {
  __shared__ unsigned short kl[2][2][64 * 64];  // [half][dbuf]
  __shared__ unsigned short vl[2][2][64 * 64];
  __shared__ unsigned short pl[8][16 * 64];
  const int tid = threadIdx.x, lane = tid & 63, w = tid >> 6;
  const int h = w >> 2, wr = w & 3;
  const int id = blockIdx.x;
  const int bh = id & 31;            // id%8 == bh%8 -> same-bh blocks share an XCD L2
  const int qt = 31 - (id >> 5);     // heavy blocks dispatched first
  const unsigned short* Qb = Q + (size_t)bh * SEQ * HD;
  const unsigned short* Kb = K + (size_t)bh * SEQ * HD;
  const unsigned short* Vb = Vt + (size_t)bh * HD * SEQ;
  const f32x4 fzero = {0.f, 0.f, 0.f, 0.f};

  const int ntot = qt + 1;
  const int nlo = (ntot + 1) >> 1;   // low half: tiles [0, nlo)
  const int nhi = ntot - nlo;        // high half: tiles [nlo, ntot)
  const int mylim = h ? nhi : nlo;
  const int kt0 = h ? nlo : 0;

  // Q fragments straight from global: wave handles q-rows qt*64 + wr*16 .. +15
  const int qrow = qt * 64 + wr * 16 + (lane & 15);
  bf16x8 qf[2];
#pragma unroll
  for (int ks = 0; ks < 2; ks++)
    qf[ks] = *(const bf16x8*)(Qb + (size_t)qrow * HD + (ks * 4 + (lane >> 4)) * 8);

  f32x4 oacc[4];
  float mrun[4], lpart[4];
#pragma unroll
  for (int nd = 0; nd < 4; nd++) oacc[nd] = fzero;
#pragma unroll
  for (int r = 0; r < 4; r++) { mrun[r] = -__builtin_inff(); lpart[r] = 0.f; }

#define STAGE(S, BUF)                                                                 \
  if ((S) < mylim) {                                                                  \
    const int kb_ = (kt0 + (S)) * 64;                                                 \
    _Pragma("unroll")                                                                 \
    for (int i = 0; i < 2; i++) {                                                     \
      int row = wr * 16 + i * 8 + (lane >> 3);                                        \
      int ch = (lane & 7) ^ (row & 7);                                                \
      gld16(&kl[h][BUF][(wr * 16 + i * 8) * 64], Kb + (size_t)(kb_ + row) * HD + ch * 8); \
      gld16(&vl[h][BUF][(wr * 16 + i * 8) * 64], Vb + (size_t)row * SEQ + kb_ + ch * 8);  \
    }                                                                                 \
  }

  STAGE(0, 0);
  __syncthreads();
  int cur = 0;

  for (int s = 0; s < nlo; s++) {
    STAGE(s + 1, cur ^ 1);          // prefetch flies during compute
    if (s < mylim) {
      const int kt = kt0 + s;
      const int kb = kt * 64;

      // ---- S = Q K^T (already log2-scaled) ----
      f32x4 sacc[4];
#pragma unroll
      for (int nk = 0; nk < 4; nk++) sacc[nk] = fzero;
#pragma unroll
      for (int ks = 0; ks < 2; ks++) {
        bf16x8 kf[4];
#pragma unroll
        for (int nk = 0; nk < 4; nk++) {
          int row = nk * 16 + (lane & 15);
          int ch = (ks * 4 + (lane >> 4)) ^ (row & 7);
          kf[nk] = *(const bf16x8*)&kl[h][cur][row * 64 + ch * 8];
        }
#pragma unroll
        for (int nk = 0; nk < 4; nk++)
          sacc[nk] = __builtin_amdgcn_mfma_f32_16x16x32_bf16(qf[ks], kf[nk], sacc[nk], 0, 0, 0);
      }

      // ---- online softmax ----
      const bool need_mask = (kt == qt);
      float p[4][4], rmax[4];
#pragma unroll
      for (int r = 0; r < 4; r++) rmax[r] = -__builtin_inff();
#pragma unroll
      for (int nk = 0; nk < 4; nk++)
#pragma unroll
        for (int r = 0; r < 4; r++) {
          float sv = sacc[nk][r];
          if (need_mask) {
            int qr = qt * 64 + wr * 16 + (lane >> 4) * 4 + r;
            int kv = kb + nk * 16 + (lane & 15);
            if (kv > qr) sv = -__builtin_inff();
          }
          p[nk][r] = sv;
          rmax[r] = fmaxf(rmax[r], sv);
        }
      bool stable = true;
#pragma unroll
      for (int r = 0; r < 4; r++) {
        rmax[r] = fmaxf(rmax[r], __shfl_xor(rmax[r], 1));
        rmax[r] = fmaxf(rmax[r], __shfl_xor(rmax[r], 2));
        rmax[r] = fmaxf(rmax[r], __shfl_xor(rmax[r], 4));
        rmax[r] = fmaxf(rmax[r], __shfl_xor(rmax[r], 8));
        stable = stable && (rmax[r] <= mrun[r] + 8.0f);
      }
      if (!__all(stable)) {          // T13 defer-max: rescale only when max grew
#pragma unroll
        for (int r = 0; r < 4; r++) {
          float mnew = fmaxf(mrun[r], rmax[r]);
          float fac = exp2f(mrun[r] - mnew);
          mrun[r] = mnew;
          lpart[r] *= fac;
#pragma unroll
          for (int nd = 0; nd < 4; nd++) oacc[nd][r] *= fac;
        }
      }
#pragma unroll
      for (int r = 0; r < 4; r++) {
        float rs = 0.f;
#pragma unroll
        for (int nk = 0; nk < 4; nk++) {
          float pv = exp2f(p[nk][r] - mrun[r]);
          p[nk][r] = pv;
          rs += pv;
        }
        lpart[r] += rs;
      }

      // ---- P -> wave-private LDS (bf16, swizzled) ----
#pragma unroll
      for (int nk = 0; nk < 4; nk++)
#pragma unroll
        for (int r = 0; r < 4; r++) {
          int prow = (lane >> 4) * 4 + r;
          int pcol = nk * 16 + (lane & 15);
          int ch = (pcol >> 3) ^ (prow & 7);
          pl[w][prow * 64 + ch * 8 + (pcol & 7)] = f2bf(p[nk][r]);
        }

      // ---- O += P @ V ----
#pragma unroll
      for (int ks = 0; ks < 2; ks++) {
        bf16x8 vf[4], pa;
#pragma unroll
        for (int nd = 0; nd < 4; nd++) {
          int row = nd * 16 + (lane & 15);
          int ch = (ks * 4 + (lane >> 4)) ^ (row & 7);
          vf[nd] = *(const bf16x8*)&vl[h][cur][row * 64 + ch * 8];
        }
        {
          int prow = lane & 15;
          int ch = (ks * 4 + (lane >> 4)) ^ (prow & 7);
          pa = *(const bf16x8*)&pl[w][prow * 64 + ch * 8];
        }
#pragma unroll
        for (int nd = 0; nd < 4; nd++)
          oacc[nd] = __builtin_amdgcn_mfma_f32_16x16x32_bf16(pa, vf[nd], oacc[nd], 0, 0, 0);
      }
    }
    __syncthreads();
    cur ^= 1;
  }
#undef STAGE

  // ---- reduce l across the 16 kv-col lanes ----
  float lred[4];
#pragma unroll
  for (int r = 0; r < 4; r++) {
    float l = lpart[r];
    l += __shfl_xor(l, 1);
    l += __shfl_xor(l, 2);
    l += __shfl_xor(l, 4);
    l += __shfl_xor(l, 8);
    lred[r] = l;
  }

  // ---- merge halves through LDS (reuse K/V space) ----
  float* o1lds = (float*)&kl[0][0][0];   // 64 rows x 64 cols f32 = 16 KB
  float* mllds = (float*)&vl[0][0][0];   // 64 rows x {m,l}
  if (h == 1) {
#pragma unroll
    for (int r = 0; r < 4; r++) {
      int row = wr * 16 + (lane >> 4) * 4 + r;
#pragma unroll
      for (int nd = 0; nd < 4; nd++)
        o1lds[row * 64 + nd * 16 + (lane & 15)] = oacc[nd][r];
      mllds[row * 2 + 0] = mrun[r];
      mllds[row * 2 + 1] = lred[r];
    }
  }
  __syncthreads();
  if (h == 0) {
    const int b = bh >> 4, hh = bh & 15;
#pragma unroll
    for (int r = 0; r < 4; r++) {
      int row = wr * 16 + (lane >> 4) * 4 + r;
      float m1 = mllds[row * 2 + 0], l1 = mllds[row * 2 + 1];
      float m0 = mrun[r], l0 = lred[r];
      float ms = fmaxf(m0, m1);              // m0 is always finite
      float f0 = exp2f(m0 - ms);
      float f1 = exp2f(m1 - ms);             // exp2(-inf)=0 covers empty high half
      float linv = 1.f / (l0 * f0 + l1 * f1);
      int t = qt * 64 + row;
#pragma unroll
      for (int nd = 0; nd < 4; nd++) {
        int d = nd * 16 + (lane & 15);
        float v1 = o1lds[row * 64 + d];
        float val = (oacc[nd][r] * f0 + v1 * f1) * linv;
        O[((size_t)(b * SEQ + t)) * DIM + hh * HD + d] = f2bf(val);
      }
    }
  }
}

// ---------------- launch ----------------
extern "C" void kernel_launch(void* const* d_in, const int* in_sizes, int n_in,
                              void* d_out, int out_size, void* d_ws, size_t ws_size,
                              hipStream_t stream) {
  const float* x     = (const float*)d_in[0];
  const float* Wqkv  = (const float*)d_in[1];
  const float* bqkv  = (const float*)d_in[2];
  const float* Wproj = (const float*)d_in[3];
  const float* bproj = (const float*)d_in[4];
  float* out = (float*)d_out;

  unsigned short* ws     = (unsigned short*)d_ws;
  unsigned short* xb_vt  = ws;                  // 4,194,304 elems: x_bf16, later V^T
  unsigned short* wqkvt  = xb_vt + 4194304;     // 3,145,728: W_qkv^T bf16
  unsigned short* wprojt = wqkvt + 3145728;     // 1,048,576: W_proj^T bf16
  unsigned short* q      = wprojt + 1048576;    // 4,194,304
  unsigned short* k      = q + 4194304;         // 4,194,304
  unsigned short* v_o    = k + 4194304;         // 4,194,304: V, later attn O
  // total 40 MB of d_ws

  k_cvt<<<2048, 256, 0, stream>>>(x, xb_vt);
  k_tr_f32bf16<<<dim3(48, 16), 256, 0, stream>>>(Wqkv, wqkvt, 1024, 3072);
  k_tr_f32bf16<<<dim3(16, 16), 256, 0, stream>>>(Wproj, wprojt, 1024, 1024);
  k_gemm_bt<0><<<dim3(24, 32), 256, 0, stream>>>(xb_vt, wqkvt, bqkv, q, NTOK, 3072, DIM);
  k_tr_v<<<dim3(32, 32), 256, 0, stream>>>(v_o, xb_vt);
  k_attn<<<dim3(1024), 512, 0, stream>>>(q, k, xb_vt, v_o);
  k_gemm_bt<1><<<dim3(8, 32), 256, 0, stream>>>(v_o, wprojt, bproj, out, NTOK, DIM, DIM);
}